// Round 4
// baseline (37.523 us; speedup 1.0000x reference)
//
#include <hip/hip_runtime.h>

// Problem constants (from reference)
#define NUM_CLUSTER 8
#define PER 16
#define BATCH 4
#define SEQ_L 96
#define D_MODEL 512
#define NI (NUM_CLUSTER * PER)        // 128 tokens
#define CHUNK (SEQ_L * D_MODEL)       // 49152 floats per (b,i) chunk
#define CHUNK_V4 (CHUNK / 4)          // 12288 float4 per chunk
#define XBLK 12                       // x-blocks per chunk
#define STRIDE (XBLK * 256)           // 3072 threads per chunk
#define ITERS (CHUNK_V4 / STRIDE)     // exactly 4 — no remainder

// Native clang vector type — __builtin_nontemporal_* requires this
// (HIP's float4 is a struct and is rejected).
typedef float f32x4 __attribute__((ext_vector_type(4)));

// Fused kernel: each block computes rank[i] via ballot (2 waves over the
// 128-entry y_pred), then does an exact-unrolled nontemporal float4 copy.
// out[(b*NI + i)] chunk <- in[(y_pred[i]*BATCH + b)*PER + rank[i]] chunk
__global__ void gather_copy(const f32x4* __restrict__ x,
                            const int* __restrict__ y_pred,
                            f32x4* __restrict__ out) {
    __shared__ int s_cnt[2];

    int bi = blockIdx.y;              // 0..511 : b*NI + i
    int b  = bi >> 7;                 // / 128
    int i  = bi & (NI - 1);           // % 128

    int c = y_pred[i];                // broadcast load, L2-resident
    int t = threadIdx.x;
    if (t < NI) {                     // waves 0 and 1 only
        bool pred = (t < i) && (y_pred[t] == c);
        unsigned long long m = __ballot(pred);
        if ((t & 63) == 0) s_cnt[t >> 6] = __popcll(m);
    }
    __syncthreads();
    int rank = s_cnt[0] + s_cnt[1];   // = #{j < i : y_pred[j] == c}

    // input layout (cluster, batch, per, L, D)
    int sc = c * (BATCH * PER) + b * PER + rank;

    const f32x4* __restrict__ src = x   + (size_t)sc * CHUNK_V4;
    f32x4* __restrict__       dst = out + (size_t)bi * CHUNK_V4;

    int k0 = blockIdx.x * 256 + t;    // 0..3071 within chunk

    // Exactly ITERS iterations, no bounds check: issue all loads, then stores.
    f32x4 v[ITERS];
#pragma unroll
    for (int u = 0; u < ITERS; ++u)
        v[u] = __builtin_nontemporal_load(src + k0 + u * STRIDE);
#pragma unroll
    for (int u = 0; u < ITERS; ++u)
        __builtin_nontemporal_store(v[u], dst + k0 + u * STRIDE);
}

extern "C" void kernel_launch(void* const* d_in, const int* in_sizes, int n_in,
                              void* d_out, int out_size, void* d_ws, size_t ws_size,
                              hipStream_t stream) {
    const float* x_enc_hf = (const float*)d_in[0];   // (8,4,16,96,512) fp32
    const int*   y_pred   = (const int*)d_in[1];     // (128,) int32
    // d_in[2] is the Python scalar B (==4), baked in as BATCH.
    float* out = (float*)d_out;                      // (4,128,96,512) fp32

    gather_copy<<<dim3(XBLK, BATCH * NI), 256, 0, stream>>>(
        (const f32x4*)x_enc_hf, y_pred, (f32x4*)out);
}

// Round 5
// 34.820 us; speedup vs baseline: 1.0776x; 1.0776x over previous
//
#include <hip/hip_runtime.h>

// Problem constants (from reference)
#define NUM_CLUSTER 8
#define PER 16
#define BATCH 4
#define SEQ_L 96
#define D_MODEL 512
#define NI (NUM_CLUSTER * PER)        // 128 tokens
#define CHUNK (SEQ_L * D_MODEL)       // 49152 floats per (b,i) chunk
#define CHUNK_V4 (CHUNK / 4)          // 12288 float4 per chunk
#define XBLK 12                       // x-blocks per chunk
#define STRIDE (XBLK * 256)           // 3072 threads per chunk
#define ITERS (CHUNK_V4 / STRIDE)     // exactly 4 — no remainder

// Native clang vector type — __builtin_nontemporal_* requires this
// (HIP's float4 is a struct and is rejected).
typedef float f32x4 __attribute__((ext_vector_type(4)));

// Fused kernel: each block computes rank[i] via ballot (2 waves over the
// 128-entry y_pred), then copies its chunk slice.
// Loads are PLAIN (input is L3-resident across replays — keep it cached);
// stores are NONTEMPORAL (streaming output must not evict input lines).
// out[(b*NI + i)] chunk <- in[(y_pred[i]*BATCH + b)*PER + rank[i]] chunk
__global__ void gather_copy(const f32x4* __restrict__ x,
                            const int* __restrict__ y_pred,
                            f32x4* __restrict__ out) {
    __shared__ int s_cnt[2];

    int bi = blockIdx.y;              // 0..511 : b*NI + i
    int b  = bi >> 7;                 // / 128
    int i  = bi & (NI - 1);           // % 128

    int c = y_pred[i];                // broadcast load, L2-resident
    int t = threadIdx.x;
    if (t < NI) {                     // waves 0 and 1 only
        bool pred = (t < i) && (y_pred[t] == c);
        unsigned long long m = __ballot(pred);
        if ((t & 63) == 0) s_cnt[t >> 6] = __popcll(m);
    }
    __syncthreads();
    int rank = s_cnt[0] + s_cnt[1];   // = #{j < i : y_pred[j] == c}

    // input layout (cluster, batch, per, L, D)
    int sc = c * (BATCH * PER) + b * PER + rank;

    const f32x4* __restrict__ src = x   + (size_t)sc * CHUNK_V4;
    f32x4* __restrict__       dst = out + (size_t)bi * CHUNK_V4;

    int k0 = blockIdx.x * 256 + t;    // 0..3071 within chunk

    // Exactly ITERS iterations, no bounds check: issue all loads, then stores.
    f32x4 v[ITERS];
#pragma unroll
    for (int u = 0; u < ITERS; ++u)
        v[u] = src[k0 + u * STRIDE];                      // plain load (cacheable)
#pragma unroll
    for (int u = 0; u < ITERS; ++u)
        __builtin_nontemporal_store(v[u], dst + k0 + u * STRIDE);  // nt store
}

extern "C" void kernel_launch(void* const* d_in, const int* in_sizes, int n_in,
                              void* d_out, int out_size, void* d_ws, size_t ws_size,
                              hipStream_t stream) {
    const float* x_enc_hf = (const float*)d_in[0];   // (8,4,16,96,512) fp32
    const int*   y_pred   = (const int*)d_in[1];     // (128,) int32
    // d_in[2] is the Python scalar B (==4), baked in as BATCH.
    float* out = (float*)d_out;                      // (4,128,96,512) fp32

    gather_copy<<<dim3(XBLK, BATCH * NI), 256, 0, stream>>>(
        (const f32x4*)x_enc_hf, y_pred, (f32x4*)out);
}